// Round 8
// baseline (106.562 us; speedup 1.0000x reference)
//
#include <hip/hip_runtime.h>
#include <hip/hip_bf16.h>

// Causal attention head. B=4, T=4096, C=384, H=16. fp32 in/out.
// Round 8 = Round 7 with the compile fix (memcpy instead of bit_cast on
// __hip_bfloat162, which is not trivially copyable).
// Flash with the S^T trick -> NO LDS, NO shuffles in loop:
//   S^T = K·Q^T (operand swap; loads unchanged) gives C layout col=query,
//   row=key. Relabel PV contraction k = q*8+j -> key i*32+(j>>2)*16+q*4+(j&3):
//   the P B-fragment is then exactly the 8 exp() values each lane already
//   holds -> P never leaves registers. V A-frag = two 8B loads of contiguous
//   keys. exp->bf16 via v_cvt_pk_bf16_f32. l is per-query -> 2 shuffles total.
//  - Key-split x8 partials to global + flash_merge (R6 scheme) retained.
//  - qkv_mfma / wconv unchanged.
// Fixed harness floor ~52us (256MB ws re-poison + restores) on top.

constexpr int B_DIM = 4;
constexpr int T_SEQ = 4096;
constexpr int C_DIM = 384;
constexpr int H_DIM = 16;
constexpr int NROW  = B_DIM * T_SEQ; // 16384

typedef __bf16 bf16x8 __attribute__((ext_vector_type(8)));
typedef float  f32x4  __attribute__((ext_vector_type(4)));

__device__ __forceinline__ unsigned short f2bf(float f) {
  unsigned int u = __builtin_bit_cast(unsigned int, f);
  u += 0x7fffu + ((u >> 16) & 1u);   // RNE (finite inputs)
  return (unsigned short)(u >> 16);
}
__device__ __forceinline__ bf16x8 as_bf16x8(uint4 u) {
  return __builtin_bit_cast(bf16x8, u);
}
__device__ __forceinline__ unsigned pk2(float a, float b) {
  float2 t; t.x = a; t.y = b;
  __hip_bfloat162 h = __float22bfloat162_rn(t);  // v_cvt_pk_bf16_f32
  unsigned u;
  __builtin_memcpy(&u, &h, 4);                   // bit_cast rejects this type
  return u;
}

// ---------------------------------------------------------------------------
// Kernel 0: W -> WT bf16, layout [m][n=16][k=384]. 18432 elements.
// ---------------------------------------------------------------------------
__global__ __launch_bounds__(256) void wconv(
    const float* __restrict__ Wk, const float* __restrict__ Wq,
    const float* __restrict__ Wv, unsigned short* __restrict__ WT) {
  const int i = blockIdx.x * 256 + threadIdx.x;   // grid 72*256 = 18432
  const int m = i / 6144;
  const int r = i - m * 6144;
  const int n = r / 384;
  const int k = r - n * 384;
  const float* __restrict__ W = (m == 0) ? Wk : (m == 1) ? Wq : Wv;
  WT[i] = f2bf(W[k * 16 + n]);
}

// ---------------------------------------------------------------------------
// Kernel 1: QKV projection via MFMA, 2-way K-split (unchanged from R5/R6).
// ---------------------------------------------------------------------------
__global__ __launch_bounds__(128) void qkv_mfma(
    const float* __restrict__ x, const unsigned short* __restrict__ WT,
    unsigned short* __restrict__ Kb,   // [NROW][16]
    unsigned short* __restrict__ Qb,   // [NROW][32] scaled + zero-padded
    unsigned short* __restrict__ VTb)  // [B][16][T]
{
  const int tid  = threadIdx.x;
  const int w    = tid >> 6;           // 0..1
  const int lane = tid & 63;
  const int quad = lane >> 4;
  const int col  = lane & 15;
  const int r0   = blockIdx.x << 4;
  const int kb   = w * 6;              // this wave's kk base

  __shared__ float mrg[12][64];

  const float4* __restrict__ xp =
      reinterpret_cast<const float4*>(x + (size_t)(r0 + col) * C_DIM) + quad * 2;
  float4 araw[12];
#pragma unroll
  for (int kk = 0; kk < 6; ++kk) {
    araw[2 * kk]     = xp[(kb + kk) * 8];
    araw[2 * kk + 1] = xp[(kb + kk) * 8 + 1];
  }

  const uint4* __restrict__ bk = reinterpret_cast<const uint4*>(
      WT + (size_t)col * 384 + quad * 8);
  const uint4* __restrict__ bq = bk + 768;    // +6144 shorts
  const uint4* __restrict__ bv = bk + 1536;   // +12288 shorts

  f32x4 ck = {0.f, 0.f, 0.f, 0.f};
  f32x4 cq = {0.f, 0.f, 0.f, 0.f};
  f32x4 cv = {0.f, 0.f, 0.f, 0.f};
#pragma unroll
  for (int kk = 0; kk < 6; ++kk) {
    uint4 pk;
    const float4 a0 = araw[2 * kk], a1 = araw[2 * kk + 1];
    pk.x = pk2(a0.x, a0.y);
    pk.y = pk2(a0.z, a0.w);
    pk.z = pk2(a1.x, a1.y);
    pk.w = pk2(a1.z, a1.w);
    const bf16x8 av = as_bf16x8(pk);
    ck = __builtin_amdgcn_mfma_f32_16x16x32_bf16(av, as_bf16x8(bk[(kb + kk) * 4]), ck, 0, 0, 0);
    cq = __builtin_amdgcn_mfma_f32_16x16x32_bf16(av, as_bf16x8(bq[(kb + kk) * 4]), cq, 0, 0, 0);
    cv = __builtin_amdgcn_mfma_f32_16x16x32_bf16(av, as_bf16x8(bv[(kb + kk) * 4]), cv, 0, 0, 0);
  }

  if (w == 1) {
#pragma unroll
    for (int r = 0; r < 4; ++r) {
      mrg[r][lane]     = ck[r];
      mrg[4 + r][lane] = cq[r];
      mrg[8 + r][lane] = cv[r];
    }
  }
  __syncthreads();
  if (w == 0) {
    const float SC = 0.25f * 1.44269504088896341f;  // softmax scale * log2(e)
#pragma unroll
    for (int r = 0; r < 4; ++r) {
      const float vk = ck[r] + mrg[r][lane];
      const float vq = cq[r] + mrg[4 + r][lane];
      const float vv = cv[r] + mrg[8 + r][lane];
      const int row = r0 + quad * 4 + r;
      Kb[row * 16 + col]      = f2bf(vk);
      Qb[row * 32 + col]      = f2bf(vq * SC);
      Qb[row * 32 + 16 + col] = 0;
      const int bb = row >> 12, t = row & 4095;
      VTb[(((size_t)(bb * 16 + col)) << 12) + t] = f2bf(vv);
    }
  }
}

// ---------------------------------------------------------------------------
// Kernel 2: flash, S^T formulation, register-resident P, zero LDS.
// grid 2048: qt = 255-(blk>>3) (heavy first), b=(blk>>1)&3, h2=blk&1;
// slot = h2*4+wave in [0,8). Wave handles 64-key chunks c = slot, slot+8, ...
// Per chunk: 4x S^T-MFMA (A=K-frag, B=Q-frag) -> C col=query,row=key;
// mask (diag chunk only, wave-uniform branch); exp2; pack own regs as P
// B-frag; 2x PV-MFMA (A=V^T key-relabeled, B=P). Partials to PO/PL.
// ---------------------------------------------------------------------------
__global__ __launch_bounds__(256, 8) void flash_v6(
    const unsigned short* __restrict__ Qb,
    const unsigned short* __restrict__ Kb,
    const unsigned short* __restrict__ VTb,
    float* __restrict__ PO, float* __restrict__ PL)
{
  const int tid  = threadIdx.x;
  const int w    = tid >> 6;
  const int lane = tid & 63;
  const int quad = lane >> 4;
  const int col  = lane & 15;
  const int qt   = 255 - (blockIdx.x >> 3);   // heavy first
  const int b    = (blockIdx.x >> 1) & 3;
  const int h2   = blockIdx.x & 1;
  const int slot = h2 * 4 + w;                // 0..7
  const int r0   = qt << 4;

  // Q as B-operand: B[k=h=quad*8+j][n=query=col]; h>=16 zero-padded.
  const bf16x8 qb = as_bf16x8(*reinterpret_cast<const uint4*>(
      Qb + (((size_t)(b * T_SEQ + r0 + col)) << 5) + quad * 8));

  f32x4 o = {0.f, 0.f, 0.f, 0.f};   // O^T frag: col=query, row(quad*4+r)=h
  float l = 0.f;                    // sum of exp for query=col (partial)

  const unsigned short* Kbase = Kb + ((size_t)(b * T_SEQ) << 4);
  const unsigned short* Vrow  = VTb + (((size_t)(b * 16 + col)) << 12); // h=col
  const int nch = (qt + 4) >> 2;

  for (int c = slot; c < nch; c += 8) {
    const int kt0 = c << 2;
    const bool diag = (kt0 + 4 > qt);   // wave-uniform: chunk touches diagonal

#pragma unroll
    for (int i = 0; i < 2; ++i) {       // 32 keys per half: tiles 2i, 2i+1
      // V A-frag, key-relabeled: lane(quad,h=col) j=0..3 -> keys base+quad*4+j,
      // j=4..7 -> keys base+16+quad*4+j  (two 8B loads of contiguous keys)
      const int vbase = kt0 * 16 + i * 32 + quad * 4;
      const uint2 v0 = *reinterpret_cast<const uint2*>(Vrow + vbase);
      const uint2 v1 = *reinterpret_cast<const uint2*>(Vrow + vbase + 16);

      float p[2][4];
#pragma unroll
      for (int t2 = 0; t2 < 2; ++t2) {
        const int kt = kt0 + 2 * i + t2;
        // K A-frag: A[m=key=col][k=h=quad*8+j]; quads 2,3 overrun the 16-short
        // row into the next row -> garbage * Q zero-pad = 0.
        const uint4 kf = *reinterpret_cast<const uint4*>(
            Kbase + (((size_t)(kt * 16 + col)) << 4) + quad * 8);
        f32x4 z = {0.f, 0.f, 0.f, 0.f};
        f32x4 s = __builtin_amdgcn_mfma_f32_16x16x32_bf16(
            as_bf16x8(kf), qb, z, 0, 0, 0);
        if (diag) {
          // mask keys beyond the query: key kt*16+quad*4+r vs query r0+col
          const int kb0 = kt * 16 + quad * 4 - r0;   // key - r0 (r added below)
#pragma unroll
          for (int r = 0; r < 4; ++r)
            if (kb0 + r > col) s[r] = -1e30f;
        }
#pragma unroll
        for (int r = 0; r < 4; ++r) {
          p[t2][r] = __builtin_amdgcn_exp2f(s[r]);   // exp2(-1e30) = 0
          l += p[t2][r];
        }
      }

      // P B-frag = this lane's own p values: b[j<4]=p[0][j], b[j>=4]=p[1][j-4]
      uint4 pb;
      pb.x = pk2(p[0][0], p[0][1]);
      pb.y = pk2(p[0][2], p[0][3]);
      pb.z = pk2(p[1][0], p[1][1]);
      pb.w = pk2(p[1][2], p[1][3]);
      const uint4 va = make_uint4(v0.x, v0.y, v1.x, v1.y);
      o = __builtin_amdgcn_mfma_f32_16x16x32_bf16(
          as_bf16x8(va), as_bf16x8(pb), o, 0, 0, 0);
    }
  }

  // l: reduce across the 4 quads sharing each query col
  l += __shfl_xor(l, 16);
  l += __shfl_xor(l, 32);

  // write partials (zeros if this wave had no chunks)
  const size_t rowbase = (size_t)b * T_SEQ + r0;
  float* pO = PO + ((size_t)slot * NROW + rowbase) * 16;
  // O^T frag -> out[query][h]: query=col, h=quad*4+r -> 16B/lane, disjoint
  *reinterpret_cast<float4*>(pO + col * 16 + quad * 4) =
      __builtin_bit_cast(float4, o);
  if (quad == 0) PL[(size_t)slot * NROW + rowbase + col] = l;
}

// ---------------------------------------------------------------------------
// Kernel 3: merge 8 partial slots: out = sum(O) / sum(l).
// ---------------------------------------------------------------------------
__global__ __launch_bounds__(256) void flash_merge(
    const float* __restrict__ PO, const float* __restrict__ PL,
    float* __restrict__ out)
{
  const int i   = blockIdx.x * 256 + threadIdx.x;   // grid 1024*256 = 262144
  const int row = i >> 4;
  float O = 0.f, L = 0.f;
#pragma unroll
  for (int s = 0; s < 8; ++s) {
    O += PO[((size_t)s * NROW) * 16 + i];
    L += PL[(size_t)s * NROW + row];
  }
  out[i] = O / L;
}

extern "C" void kernel_launch(void* const* d_in, const int* in_sizes, int n_in,
                              void* d_out, int out_size, void* d_ws, size_t ws_size,
                              hipStream_t stream) {
  const float* x  = (const float*)d_in[0];
  const float* Wk = (const float*)d_in[1];
  const float* Wq = (const float*)d_in[2];
  const float* Wv = (const float*)d_in[3];
  float* outp = (float*)d_out;

  // ws: Qb [NROW*32]sh | Kb [NROW*16]sh | 64 slack | VTb [NROW*16]sh |
  //     WT [18432]sh | PO [8*NROW*16]f32 | PL [8*NROW]f32   (~11 MB total)
  unsigned short* Qb  = (unsigned short*)d_ws;
  unsigned short* Kb  = Qb + (size_t)NROW * 32;
  unsigned short* VTb = Kb + (size_t)NROW * 16 + 64;
  unsigned short* WT  = VTb + (size_t)NROW * 16;
  float* PO = (float*)(WT + 18432);
  float* PL = PO + (size_t)8 * NROW * 16;

  wconv<<<72, 256, 0, stream>>>(Wk, Wq, Wv, WT);
  qkv_mfma<<<1024, 128, 0, stream>>>(x, WT, Kb, Qb, VTb);
  flash_v6<<<2048, 256, 0, stream>>>(Qb, Kb, VTb, PO, PL);
  flash_merge<<<1024, 256, 0, stream>>>(PO, PL, outp);
}